// Round 4
// baseline (7055.905 us; speedup 1.0000x reference)
//
#include <hip/hip_runtime.h>
#include <stdint.h>

// BetterMCMC R14: kill the two exposed-latency terms left after R13.
//  (a) s_pairw reinstated SOLELY as an O(1) splitv lookup (R11-verified maintenance
//      formula; entries are exact bigram elements -> ed bit-identical to R13).
//      splitv: global load (~300-600cy serial) -> LDS read (~120cy).
//  (b) All pos-only accept inputs prefetched in Phase A (hidden): brg loaded fresh
//      from committed perm (plA/prA speculation machinery deleted), remL/remR,
//      startv/endv candidates, stm/etm. Post-B1 serial: ~800 -> ~350 cy.
//  (c) Reject-branch rows (tmR = perm[pos_nxt], known pre-argmax) staged
//      speculatively during Phase A -> staging wait vanishes on reject steps;
//      accept steps load tmA rows post-B_mid as before.
// Phase A logits/argmax, stash, commit, emit: R13 verbatim. Zero numerical change.

#define NW 4096
#define NSTEPS 2559
#define NTHREADS 1024
#define NWAVES 16

typedef unsigned long long u64;
typedef uint32_t u32;
typedef unsigned short u16;

__device__ __forceinline__ u32 rotl32(u32 v, u32 r) { return (v << r) | (v >> (32u - r)); }

// Threefry-2x32, 20 rounds, exactly as jax/_src/prng.py threefry2x32.
__device__ __forceinline__ void tf2x32(u32 k0, u32 k1, u32 x0, u32 x1, u32* o0, u32* o1) {
  u32 ks2 = k0 ^ k1 ^ 0x1BD11BDAu;
  x0 += k0; x1 += k1;
#define TFR(r0, r1, r2, r3)                      \
  x0 += x1; x1 = rotl32(x1, r0); x1 ^= x0;       \
  x0 += x1; x1 = rotl32(x1, r1); x1 ^= x0;       \
  x0 += x1; x1 = rotl32(x1, r2); x1 ^= x0;       \
  x0 += x1; x1 = rotl32(x1, r3); x1 ^= x0;
  TFR(13, 15, 26, 6)  x0 += k1;  x1 += ks2 + 1u;
  TFR(17, 29, 16, 24) x0 += ks2; x1 += k0 + 2u;
  TFR(13, 15, 26, 6)  x0 += k0;  x1 += k1 + 3u;
  TFR(17, 29, 16, 24) x0 += k1;  x1 += ks2 + 4u;
  TFR(13, 15, 26, 6)  x0 += ks2; x1 += k0 + 5u;
#undef TFR
  *o0 = x0; *o1 = x1;
}

__device__ __forceinline__ float unif01(u32 bits) {
  return __uint_as_float((bits >> 9) | 0x3f800000u) - 1.0f;
}

__device__ __forceinline__ u32 fkey(float f) {
  u32 b = __float_as_uint(f);
  return b ^ ((b >> 31) ? 0xFFFFFFFFu : 0x80000000u);
}

// ---------------- DPP helpers (VALU, no LDS pipe) ----------------
// 0x138 wave_shr1: dest lane n <- lane n-1.  0x130 wave_shl1: dest lane n <- lane n+1.
// bound_ctrl=true -> invalid src = 0.

template <int CTRL>
__device__ __forceinline__ u32 dpp32(u32 v) {
  return (u32)__builtin_amdgcn_update_dpp(0, (int)v, CTRL, 0xF, 0xF, true);
}

template <int CTRL>
__device__ __forceinline__ void dppmax64(u32& hi, u32& lo) {
  u32 h2 = dpp32<CTRL>(hi);
  u32 l2 = dpp32<CTRL>(lo);
  bool g = (h2 > hi) || (h2 == hi && l2 > lo);
  hi = g ? h2 : hi;
  lo = g ? l2 : lo;
}

// wave64 reduce; result valid in lane 63 (zero-fill: key 0 never wins)
__device__ __forceinline__ u64 wave_max_u64(u64 key) {
  u32 lo = (u32)key, hi = (u32)(key >> 32);
  dppmax64<0x111>(hi, lo); dppmax64<0x112>(hi, lo);
  dppmax64<0x114>(hi, lo); dppmax64<0x118>(hi, lo);
  dppmax64<0x142>(hi, lo); dppmax64<0x143>(hi, lo);
  return ((u64)hi << 32) | lo;
}

// 16-lane butterfly -> ALL lanes hold the result
__device__ __forceinline__ u64 bfly16_max_u64(u64 key) {
  u32 lo = (u32)key, hi = (u32)(key >> 32);
  dppmax64<0xB1>(hi, lo); dppmax64<0x4E>(hi, lo);
  dppmax64<0x141>(hi, lo); dppmax64<0x140>(hi, lo);
  return ((u64)hi << 32) | lo;
}

// ---------------- prep kernels (massively parallel) ----------------

#define TT 32
__global__ void transpose_k(const float* __restrict__ in, float* __restrict__ out) {
  __shared__ float tile[TT][TT + 1];
  int x = blockIdx.x * TT + threadIdx.x;
  int y = blockIdx.y * TT + threadIdx.y;
  for (int j = 0; j < TT; j += 8) tile[threadIdx.y + j][threadIdx.x] = in[(u64)(y + j) * NW + x];
  __syncthreads();
  x = blockIdx.y * TT + threadIdx.x;
  y = blockIdx.x * TT + threadIdx.y;
  for (int j = 0; j < TT; j += 8) out[(u64)(y + j) * NW + x] = tile[threadIdx.x][threadIdx.y + j];
}

// Natural layout: gumb[t*NW + i] = gumbel for element i at step t.
__global__ void gumbel_k(float* __restrict__ gumb) {
  long long idx = (long long)blockIdx.x * blockDim.x + threadIdx.x;
  if (idx >= (long long)NSTEPS * NW) return;
  int t = (int)(idx >> 12);
  int i = (int)(idx & (NW - 1));
  u32 kt0, kt1, kc0, kc1, ba, bb;
  tf2x32(0u, 42u, 0u, (u32)t, &kt0, &kt1);
  tf2x32(kt0, kt1, 0u, 1u, &kc0, &kc1);
  tf2x32(kc0, kc1, 0u, (u32)i, &ba, &bb);
  float u = unif01(ba ^ bb);
  if (u == 0.0f) u = 1.17549435e-38f;
  float t1 = (float)log((double)u);
  float t2 = (float)log((double)(-t1));
  gumb[idx] = -t2;
}

__global__ void posu_k(int* __restrict__ posArr, float* __restrict__ uArr) {
  int t = blockIdx.x * blockDim.x + threadIdx.x;
  if (t >= NSTEPS) return;
  u32 kt0, kt1, kp0, kp1, ku0, ku1, k2a, k2b, ra, rb, ua, ub;
  tf2x32(0u, 42u, 0u, (u32)t, &kt0, &kt1);
  tf2x32(kt0, kt1, 0u, 0u, &kp0, &kp1);
  tf2x32(kt0, kt1, 0u, 2u, &ku0, &ku1);
  tf2x32(kp0, kp1, 0u, 1u, &k2a, &k2b);
  tf2x32(k2a, k2b, 0u, 0u, &ra, &rb);
  posArr[t] = (int)((ra ^ rb) & (u32)(NW - 1));
  tf2x32(ku0, ku1, 0u, 0u, &ua, &ub);
  uArr[t] = unif01(ua ^ ub);
}

// ---------------- main chain kernel ----------------

// proposed sample element at index idx (reads pre-commit s_perm; uses np/pos/tm)
#define SAMPLE_AT(idx)                                                        \
  ((idx) < np ? (int)s_perm[(idx) + ((idx) >= pos)]                           \
              : ((idx) == np ? tm                                             \
                             : (int)s_perm[((idx)-1) + (((idx)-1) >= pos)]))

__global__ __launch_bounds__(NTHREADS)
void mcmc_fast12(const float* __restrict__ bigram,
                 const float* __restrict__ bigT,
                 const float* __restrict__ gumb,
                 const int* __restrict__ posArr,
                 const float* __restrict__ uArr,
                 const float* __restrict__ startv,
                 const float* __restrict__ endv,
                 int* __restrict__ out) {
  __shared__ u16    s_perm[NW];       // 8 KB
  __shared__ float2 s_rows[NW];       // 32 KB  (T[w], B[w]) for current tm
  __shared__ float  s_pairw[NW];      // 16 KB  pair weights of current perm
  __shared__ u64    s_redu[NWAVES];
  __shared__ float  s_stm, s_etm, s_lpos, s_brgS, s_vn1, s_vn2;
  __shared__ int    s_accs;

  const int tid = threadIdx.x;
  const int lane = tid & 63;
  const int wid = tid >> 6;
  const int j0 = tid * 4;             // first owned element

  // ---- init: identity perm; pairw; stage step-0 rows (interleaved) ----
  for (int i = tid; i < NW; i += NTHREADS) s_perm[i] = (u16)i;
#pragma unroll
  for (int k = 0; k < 4; ++k) {
    int j = j0 + k;
    s_pairw[j] = (j < NW - 1) ? bigram[(u64)j * NW + (j + 1)] : 0.0f;
  }

  int pos = posArr[0];
  int tm = pos;                        // identity perm: perm[pos] == pos
  {
    float4 rb4 = ((const float4*)(bigram + (u64)tm * NW))[tid];
    float4 rt4 = ((const float4*)(bigT + (u64)tm * NW))[tid];
    ((float4*)(&s_rows[j0]))[0] = make_float4(rt4.x, rb4.x, rt4.y, rb4.y);
    ((float4*)(&s_rows[j0]))[1] = make_float4(rt4.z, rb4.z, rt4.w, rb4.w);
  }
  if (tid == 0) { s_stm = startv[tm]; s_etm = endv[tm]; }

  // wave0-carried uniform chain state (garbage in other waves, never read there)
  float u_cur = uArr[0];
  float start_cur = startv[0];
  float end_cur = endv[NW - 1];

  float4 g4 = ((const float4*)gumb)[tid];
  __syncthreads();

  for (int t = 0; t < NSTEPS; ++t) {
    // ---- Phase A ----
    const float gg[4] = {g4.x, g4.y, g4.z, g4.w};
    int pos_nxt; float u_nxt;
    {
      int tn = (t + 1 < NSTEPS) ? (t + 1) : (NSTEPS - 1);
      g4 = ((const float4*)(gumb + ((u64)tn << 12)))[tid];   // for step t+1
      pos_nxt = posArr[tn];
      u_nxt = uArr[tn];
    }
    // speculative reject-branch staging (tmR known pre-argmax)
    const int tmR = (int)s_perm[pos_nxt];
    const float4 rbR = ((const float4*)(bigram + (u64)tmR * NW))[tid];
    const float4 rtR = ((const float4*)(bigT + (u64)tmR * NW))[tid];
    float stmR = 0.0f, etmR = 0.0f;
    if (tid == 0) { stmR = startv[tmR]; etmR = endv[tmR]; }

    // perm block + neighbors (R13 verbatim)
    ushort4 pq = ((const ushort4*)s_perm)[tid];              // perm[j0..j0+3]
    const int p0i = pq.x, p1i = pq.y, p2i = pq.z, p3i = pq.w;
    int pm1, pp4;
    {
      u32 lo = (u32)pq.x | ((u32)pq.y << 16);
      u32 hi = (u32)pq.z | ((u32)pq.w << 16);
      pm1 = (int)(dpp32<0x138>(hi) >> 16);                   // lane-1's p3 = perm[j0-1]
      pp4 = (int)(dpp32<0x130>(lo) & 0xFFFFu);               // lane+1's p0 = perm[j0+4]
      if (lane == 0)  pm1 = (tid > 0) ? (int)s_perm[j0 - 1] : 0;
      if (lane == 63) pp4 = (tid < NTHREADS - 1) ? (int)s_perm[j0 + 4] : 0;
    }
    // pairw block + neighbors (same DPP pattern)
    float4 pwq = ((const float4*)s_pairw)[tid];              // pairw[j0..j0+3]
    float pwm1, pwp4;
    {
      pwm1 = __uint_as_float(dpp32<0x138>(__float_as_uint(pwq.w)));
      pwp4 = __uint_as_float(dpp32<0x130>(__float_as_uint(pwq.x)));
      if (lane == 0)  pwm1 = (tid > 0) ? s_pairw[j0 - 1] : 0.0f;
      if (lane == 63) pwp4 = (tid < NTHREADS - 1) ? s_pairw[j0 + 4] : 0.0f;
    }

    // wave0 uniform prefetch of all pos-only accept inputs (hidden under Phase A)
    float stm_r = 0.0f, etm_r = 0.0f, remL = 0.0f, remR = 0.0f, brgv = 0.0f;
    float sv0m = 0.0f, ev1m = 0.0f;
    if (wid == 0) {
      stm_r = s_stm; etm_r = s_etm;
      int pl = (pos > 0) ? (int)s_perm[pos - 1] : 0;
      int pr = (pos < NW - 1) ? (int)s_perm[pos + 1] : 0;
      if (pos > 0)      remL = s_rows[pl].x;                 // B[P[pos-1], tm]
      if (pos < NW - 1) remR = s_rows[pr].y;                 // B[tm, P[pos+1]]
      if (pos > 0 && pos < NW - 1) brgv = bigram[(u64)pl * NW + pr];  // fresh bridge
      sv0m = startv[(int)s_perm[(0 >= pos) ? 1 : 0]];
      ev1m = endv[(int)s_perm[(NW - 2) + ((NW - 2) >= pos)]];
      if (lane == 0) s_brgS = brgv;
    }

    // perm2 values for owned j (register selects)
    const int w0 = (j0     >= pos) ? p1i : p0i;
    const int w1 = (j0 + 1 >= pos) ? p2i : p1i;
    const int w2 = (j0 + 2 >= pos) ? p3i : p2i;
    const int w3 = (j0 + 3 >= pos) ? pp4 : p3i;
    const int wprev = ((j0 - 1) >= pos) ? p0i : pm1;         // perm2[j0-1]
    // interleaved gathers: f_k = (T[w_k], B[w_k])
    const float2 f0 = s_rows[w0];
    const float2 f1 = s_rows[w1];
    const float2 f2 = s_rows[w2];
    const float2 f3 = s_rows[w3];
    float tprev = __uint_as_float(dpp32<0x138>(__float_as_uint(f3.x)));
    if (lane == 0 && tid > 0) tprev = s_rows[wprev].x;
    // logits (bit-identical adds: T + B)
    float li0 = tprev + f0.y;
    float li1 = f0.x + f1.y;
    float li2 = f1.x + f2.y;
    float li3 = f2.x + f3.y;
    if (tid == 0)            li0 = s_stm + f0.y;
    if (tid == NTHREADS - 1) li3 = s_etm + f2.x;
    if ((pos >> 2) == tid) {
      int k = pos & 3;
      s_lpos = (k == 0) ? li0 : ((k == 1) ? li1 : ((k == 2) ? li2 : li3));
    }
    u64 best;
    {
      u64 b0 = ((u64)fkey(gg[0] + li0) << 32) | (u32)(NW - 1 - j0);
      u64 b1 = ((u64)fkey(gg[1] + li1) << 32) | (u32)(NW - 2 - j0);
      u64 b2 = ((u64)fkey(gg[2] + li2) << 32) | (u32)(NW - 3 - j0);
      u64 b3 = ((u64)fkey(gg[3] + li3) << 32) | (u32)(NW - 4 - j0);
      best = b0 > b1 ? b0 : b1;
      u64 b23 = b2 > b3 ? b2 : b3;
      if (b23 > best) best = b23;
    }
    best = wave_max_u64(best);
    if (lane == 63) s_redu[wid] = best;
    __syncthreads();                                                  // B1

    // ---- Phase B ----
    int np;
    {
      u64 bb = bfly16_max_u64(s_redu[lane & 15]);
      np = NW - 1 - (int)(bb & 0xFFFFFFFFu);
    }
    const int tmA = SAMPLE_AT(pos_nxt);
    // register stash (R13 verbatim)
    ushort4 st;
    st.x = (j0     < np) ? (u16)w0 : ((j0     == np) ? (u16)tm : (u16)wprev);
    st.y = (j0 + 1 < np) ? (u16)w1 : ((j0 + 1 == np) ? (u16)tm : (u16)w0);
    st.z = (j0 + 2 < np) ? (u16)w2 : ((j0 + 2 == np) ? (u16)tm : (u16)w1);
    st.w = (j0 + 3 < np) ? (u16)w3 : ((j0 + 3 == np) ? (u16)tm : (u16)w2);
    // pairw update candidates (old pairw in registers; np-1/np slots patched in C)
    const float brgAll = s_brgS;
    float nv0, nv1, nv2, nv3;
    {
      float vA0 = (j0     < pos - 1) ? pwq.x : pwq.y;
      float vB0 = (j0 - 1 < pos - 1) ? pwm1  : pwq.x;
      nv0 = (j0 < np) ? vA0 : vB0;
      int kk0 = (j0 < np) ? j0 : j0 - 1;
      if (kk0 == pos - 1) nv0 = brgAll;

      float vA1 = (j0 + 1 < pos - 1) ? pwq.y : pwq.z;
      float vB1 = (j0     < pos - 1) ? pwq.x : pwq.y;
      nv1 = (j0 + 1 < np) ? vA1 : vB1;
      int kk1 = (j0 + 1 < np) ? j0 + 1 : j0;
      if (kk1 == pos - 1) nv1 = brgAll;

      float vA2 = (j0 + 2 < pos - 1) ? pwq.z : pwq.w;
      float vB2 = (j0 + 1 < pos - 1) ? pwq.y : pwq.z;
      nv2 = (j0 + 2 < np) ? vA2 : vB2;
      int kk2 = (j0 + 2 < np) ? j0 + 2 : j0 + 1;
      if (kk2 == pos - 1) nv2 = brgAll;

      float vA3 = (j0 + 3 < pos - 1) ? pwq.w : pwp4;
      float vB3 = (j0 + 2 < pos - 1) ? pwq.z : pwq.w;
      nv3 = (j0 + 3 < np) ? vA3 : vB3;
      int kk3 = (j0 + 3 < np) ? j0 + 3 : j0 + 2;
      if (kk3 == pos - 1) nv3 = brgAll;
    }
    // wave0 accept decision (short serial chain: l_s/r_s -> vnpm1/vnp; splitv from LDS)
    if (wid == 0) {
      int ls_i = (np >= 1) ? ((np - 1) + ((np - 1) >= pos)) : 0;
      int rs_i = (np <= NW - 2) ? (np + (np >= pos)) : 0;
      const int l_s = (int)s_perm[ls_i];
      const int r_s = (int)s_perm[rs_i];
      float vnpm1 = (np >= 1)      ? s_rows[l_s].x : 0.0f;
      float vnp   = (np <= NW - 2) ? s_rows[r_s].y : 0.0f;
      float splitv = 0.0f;
      if (np > 0 && np < NW - 1) {
        int k_s = (np - 1) + ((np - 1) >= pos);
        splitv = (np == pos) ? brgv : s_pairw[k_s];          // O(1) LDS lookup
      }
      float sv0 = (np > 0) ? sv0m : stm_r;
      float ev1 = (np < NW - 1) ? ev1m : etm_r;
      float lposv = s_lpos;
      double delta = 0.0;
      if (pos > 0)                 delta -= (double)remL;
      if (pos < NW - 1)            delta -= (double)remR;
      if (pos > 0 && pos < NW - 1) delta += (double)brgv;
      if (np > 0)                  delta += (double)vnpm1;
      if (np < NW - 1)             delta += (double)vnp;
      if (np > 0 && np < NW - 1)   delta -= (double)splitv;
      delta += ((double)sv0 - (double)start_cur) + ((double)ev1 - (double)end_cur);
      float lnp = (np == 0) ? (stm_r + vnp)
                : ((np == NW - 1) ? (etm_r + vnpm1) : (vnpm1 + vnp));
      double ed = delta + ((double)lnp - (double)lposv);
      float a = fminf(1.0f, expf((float)ed));
      int acc = (a > u_cur) ? 1 : 0;
      if (lane == 0) { s_accs = acc; s_vn1 = vnpm1; s_vn2 = vnp; }
      if (acc) { start_cur = sv0; end_cur = ev1; }
    }
    __syncthreads();                                                  // B_mid

    // ---- Phase C: select branch; commit; stage rows ----
    const int acc = s_accs;
    const int tm_next = acc ? tmA : tmR;
    float4 rb = rbR, rt = rtR;
    if (acc) {
      rb = ((const float4*)(bigram + (u64)tm_next * NW))[tid];
      rt = ((const float4*)(bigT + (u64)tm_next * NW))[tid];
    }
    if (tid == 0) {
      s_stm = acc ? startv[tm_next] : stmR;
      s_etm = acc ? endv[tm_next] : etmR;
    }
    if (acc) {
      ((ushort4*)s_perm)[tid] = st;                          // 1 ds_write_b64
      float vn1 = s_vn1, vn2 = s_vn2;
      float o0 = (j0     == np - 1) ? vn1 : ((j0     == np) ? vn2 : nv0);
      float o1 = (j0 + 1 == np - 1) ? vn1 : ((j0 + 1 == np) ? vn2 : nv1);
      float o2 = (j0 + 2 == np - 1) ? vn1 : ((j0 + 2 == np) ? vn2 : nv2);
      float o3 = (j0 + 3 == np - 1) ? vn1 : ((j0 + 3 == np) ? vn2 : nv3);
      if (j0 + 3 >= NW - 1) o3 = 0.0f;                       // pairw[NW-1] stays 0
      ((float4*)s_pairw)[tid] = make_float4(o0, o1, o2, o3); // 1 ds_write_b128
    }
    ((float4*)(&s_rows[j0]))[0] = make_float4(rt.x, rb.x, rt.y, rb.y);
    ((float4*)(&s_rows[j0]))[1] = make_float4(rt.z, rb.z, rt.w, rb.w);
    tm = tm_next;
    pos = pos_nxt;
    u_cur = u_nxt;
    __syncthreads();                                                  // B_end

    // ---- emit thinned sample ----
    if ((t % 10) == 8) {
      int row = (t - 8) / 10;
      ushort4 p4 = ((const ushort4*)s_perm)[tid];
      int4 o4;
      o4.x = (int)p4.x; o4.y = (int)p4.y; o4.z = (int)p4.z; o4.w = (int)p4.w;
      ((int4*)(out + (u64)row * NW))[tid] = o4;
    }
  }
}

// ---------------- fallback (R2 kernel, verified) ----------------

__global__ __launch_bounds__(NTHREADS)
void mcmc_kernel(const float* __restrict__ bigram,
                 const float* __restrict__ startv,
                 const float* __restrict__ endv,
                 int* __restrict__ out) {
  __shared__ int    s_perm[NW];
  __shared__ float  s_logit[NW];
  __shared__ float  s_gath[NW];
  __shared__ float  s_redf[NWAVES];
  __shared__ u64    s_redu[NWAVES];
  __shared__ double s_redd[NWAVES];
  __shared__ float  s_m, s_Z, s_w;
  __shared__ int    s_pos, s_tm, s_np, s_acc;
  __shared__ u32    s_kcat0, s_kcat1, s_ku0, s_ku1;

  const int tid = threadIdx.x;
  const int lane = tid & 63;
  const int wid = tid >> 6;

  for (int i = tid; i < NW; i += NTHREADS) s_perm[i] = i;
  for (int j = tid; j < NW - 1; j += NTHREADS) s_gath[j] = bigram[(u64)j * NW + (j + 1)];
  __syncthreads();
  if (tid == 0) {
    float S = 0.0f;
    for (int j = 0; j < NW - 1; ++j) S += s_gath[j];
    S = S + startv[0];
    S = S + endv[NW - 1];
    s_w = S;
  }
  __syncthreads();

  for (int t = 0; t < NSTEPS; ++t) {
    if (tid == 0) {
      u32 kt0, kt1;
      tf2x32(0u, 42u, 0u, (u32)t, &kt0, &kt1);
      u32 kp0, kp1, kc0, kc1, ku0, ku1;
      tf2x32(kt0, kt1, 0u, 0u, &kp0, &kp1);
      tf2x32(kt0, kt1, 0u, 1u, &kc0, &kc1);
      tf2x32(kt0, kt1, 0u, 2u, &ku0, &ku1);
      u32 k2a, k2b, ra, rb;
      tf2x32(kp0, kp1, 0u, 1u, &k2a, &k2b);
      tf2x32(k2a, k2b, 0u, 0u, &ra, &rb);
      int pos = (int)((ra ^ rb) & (u32)(NW - 1));
      s_pos = pos;
      s_tm = s_perm[pos];
      s_kcat0 = kc0; s_kcat1 = kc1; s_ku0 = ku0; s_ku1 = ku1;
    }
    __syncthreads();
    const int pos = s_pos, tm = s_tm;

    float lmax = -3.402823466e+38f;
    for (int i = tid; i < NW; i += NTHREADS) {
      float li;
      if (i == 0) {
        int r = s_perm[(0 >= pos) ? 1 : 0];
        li = startv[tm] + bigram[(u64)tm * NW + r];
      } else if (i == NW - 1) {
        int l = s_perm[((NW - 2) >= pos) ? (NW - 1) : (NW - 2)];
        li = endv[tm] + bigram[(u64)l * NW + tm];
      } else {
        int l = s_perm[((i - 1) >= pos) ? i : (i - 1)];
        int r = s_perm[(i >= pos) ? (i + 1) : i];
        li = bigram[(u64)l * NW + tm] + bigram[(u64)tm * NW + r];
      }
      s_logit[i] = li;
      lmax = fmaxf(lmax, li);
    }
    for (int o = 32; o > 0; o >>= 1) lmax = fmaxf(lmax, __shfl_down(lmax, o, 64));
    if (lane == 0) s_redf[wid] = lmax;
    __syncthreads();
    if (tid == 0) {
      float m = s_redf[0];
      for (int w = 1; w < NWAVES; ++w) m = fmaxf(m, s_redf[w]);
      s_m = m;
    }
    __syncthreads();
    const float m = s_m;

    double zacc = 0.0;
    u64 best = 0;
    const u32 kc0 = s_kcat0, kc1 = s_kcat1;
    for (int i = tid; i < NW; i += NTHREADS) {
      float li = s_logit[i];
      float ex = (float)exp((double)(li - m));
      zacc += (double)ex;
      u32 ba, bb;
      tf2x32(kc0, kc1, 0u, (u32)i, &ba, &bb);
      float u = unif01(ba ^ bb);
      if (u == 0.0f) u = 1.17549435e-38f;
      float t1 = (float)log((double)u);
      float t2 = (float)log((double)(-t1));
      float g = -t2;
      float sv = g + li;
      u64 key = ((u64)fkey(sv) << 32) | (u32)(NW - 1 - i);
      if (key > best) best = key;
    }
    for (int o = 32; o > 0; o >>= 1) {
      u64 w = __shfl_down(best, o, 64);
      if (w > best) best = w;
      zacc += __shfl_down(zacc, o, 64);
    }
    if (lane == 0) { s_redu[wid] = best; s_redd[wid] = zacc; }
    __syncthreads();
    if (tid == 0) {
      u64 b = s_redu[0]; double z = s_redd[0];
      for (int w = 1; w < NWAVES; ++w) {
        if (s_redu[w] > b) b = s_redu[w];
        z += s_redd[w];
      }
      s_np = NW - 1 - (int)(b & 0xFFFFFFFFu);
      s_Z = (float)z;
    }
    __syncthreads();
    const int np = s_np;

    for (int j = tid; j < NW - 1; j += NTHREADS) {
      int a = (j < np) ? s_perm[j + (j >= pos)]
                       : ((j == np) ? tm : s_perm[(j - 1) + ((j - 1) >= pos)]);
      int j1 = j + 1;
      int b = (j1 < np) ? s_perm[j1 + (j1 >= pos)]
                        : ((j1 == np) ? tm : s_perm[(j1 - 1) + ((j1 - 1) >= pos)]);
      s_gath[j] = bigram[(u64)a * NW + b];
    }
    __syncthreads();

    if (tid == 0) {
      float S = 0.0f;
      for (int j = 0; j < NW - 1; ++j) S += s_gath[j];
      int s0 = (0 < np) ? s_perm[(0 >= pos) ? 1 : 0] : tm;
      int sl = ((NW - 1) == np) ? tm : s_perm[(NW - 2) + ((NW - 2) >= pos)];
      S = S + startv[s0];
      S = S + endv[sl];
      float dw = S - s_w;
      float e1 = (float)exp((double)dw);
      float en = (float)exp((double)(s_logit[np] - m));
      float eo = (float)exp((double)(s_logit[pos] - m));
      float pn = en / s_Z;
      float po = eo / s_Z;
      float acc = e1 * pn;
      acc = acc / po;
      acc = fminf(1.0f, acc);
      u32 ua, ub;
      tf2x32(s_ku0, s_ku1, 0u, 0u, &ua, &ub);
      float u = unif01(ua ^ ub);
      int accept = (acc > u) ? 1 : 0;
      s_acc = accept;
      if (accept) s_w = S;
    }
    __syncthreads();

    int stash[4];
    if (s_acc) {
      for (int k = 0; k < 4; ++k) {
        int i = tid + k * NTHREADS;
        stash[k] = (i < np) ? s_perm[i + (i >= pos)]
                            : ((i == np) ? tm : s_perm[(i - 1) + ((i - 1) >= pos)]);
      }
    }
    __syncthreads();
    if (s_acc) {
      for (int k = 0; k < 4; ++k) {
        int i = tid + k * NTHREADS;
        s_perm[i] = stash[k];
      }
    }
    __syncthreads();

    if (((t + 1) % 10) == 9) {
      int row = (t - 8) / 10;
      for (int i = tid; i < NW; i += NTHREADS) out[(u64)row * NW + i] = s_perm[i];
    }
    __syncthreads();
  }
}

extern "C" void kernel_launch(void* const* d_in, const int* in_sizes, int n_in,
                              void* d_out, int out_size, void* d_ws, size_t ws_size,
                              hipStream_t stream) {
  const float* bigram = (const float*)d_in[1];
  const float* startv = (const float*)d_in[2];
  const float* endv   = (const float*)d_in[3];
  int* out = (int*)d_out;

  const size_t needT = (size_t)NW * NW * sizeof(float);        // 64 MB
  const size_t needG = (size_t)NSTEPS * NW * sizeof(float);    // ~41.9 MB
  const size_t needP = (size_t)NSTEPS * (sizeof(int) + sizeof(float));

  if (ws_size >= needT + needG + needP) {
    float* bigT = (float*)d_ws;
    float* gumb = (float*)((char*)d_ws + needT);
    int* posArr = (int*)((char*)d_ws + needT + needG);
    float* uArr = (float*)((char*)d_ws + needT + needG + (size_t)NSTEPS * sizeof(int));
    hipLaunchKernelGGL(transpose_k, dim3(NW / TT, NW / TT), dim3(TT, 8), 0, stream,
                       bigram, bigT);
    long long ng = (long long)NSTEPS * NW;
    hipLaunchKernelGGL(gumbel_k, dim3((unsigned)((ng + 255) / 256)), dim3(256), 0, stream,
                       gumb);
    hipLaunchKernelGGL(posu_k, dim3((NSTEPS + 255) / 256), dim3(256), 0, stream,
                       posArr, uArr);
    hipLaunchKernelGGL(mcmc_fast12, dim3(1), dim3(NTHREADS), 0, stream,
                       bigram, bigT, gumb, posArr, uArr, startv, endv, out);
  } else {
    hipLaunchKernelGGL(mcmc_kernel, dim3(1), dim3(NTHREADS), 0, stream,
                       bigram, startv, endv, out);
  }
}

// Round 5
// 6603.792 us; speedup vs baseline: 1.0685x; 1.0685x over previous
//
#include <hip/hip_runtime.h>
#include <stdint.h>

// BetterMCMC R15: R14's ideas with accept-conditional (lazy) execution, exploiting the
// measured ~12% accept rate.
//  - np/stash/pairw-maintenance all move into Phase C under uniform if(acc): waves 1-15
//    do no Phase-B work; reject-step Phase C is ~100cy (speculatively staged rows).
//  - perm/pairw blocks carried in REGISTERS across steps (pq/pwq); LDS copies kept for
//    random-access readers. Deletes 32 LDS block reads/step. Register-based emit.
//  - wave0 pos-term prefetch issued at Phase-A TOP (overlaps gathers, no longer gates
//    B1); posArr/uArr double-buffered one extra step so tmR staging issues immediately.
//  - wave0 Phase B: splitv from pairw LDS (R14-verified), tmA computed once + broadcast.
// Numerics bit-identical to R14 (absmax=0 there); only instruction placement changed.

#define NW 4096
#define NSTEPS 2559
#define NTHREADS 1024
#define NWAVES 16

typedef unsigned long long u64;
typedef uint32_t u32;
typedef unsigned short u16;

__device__ __forceinline__ u32 rotl32(u32 v, u32 r) { return (v << r) | (v >> (32u - r)); }

// Threefry-2x32, 20 rounds, exactly as jax/_src/prng.py threefry2x32.
__device__ __forceinline__ void tf2x32(u32 k0, u32 k1, u32 x0, u32 x1, u32* o0, u32* o1) {
  u32 ks2 = k0 ^ k1 ^ 0x1BD11BDAu;
  x0 += k0; x1 += k1;
#define TFR(r0, r1, r2, r3)                      \
  x0 += x1; x1 = rotl32(x1, r0); x1 ^= x0;       \
  x0 += x1; x1 = rotl32(x1, r1); x1 ^= x0;       \
  x0 += x1; x1 = rotl32(x1, r2); x1 ^= x0;       \
  x0 += x1; x1 = rotl32(x1, r3); x1 ^= x0;
  TFR(13, 15, 26, 6)  x0 += k1;  x1 += ks2 + 1u;
  TFR(17, 29, 16, 24) x0 += ks2; x1 += k0 + 2u;
  TFR(13, 15, 26, 6)  x0 += k0;  x1 += k1 + 3u;
  TFR(17, 29, 16, 24) x0 += k1;  x1 += ks2 + 4u;
  TFR(13, 15, 26, 6)  x0 += ks2; x1 += k0 + 5u;
#undef TFR
  *o0 = x0; *o1 = x1;
}

__device__ __forceinline__ float unif01(u32 bits) {
  return __uint_as_float((bits >> 9) | 0x3f800000u) - 1.0f;
}

__device__ __forceinline__ u32 fkey(float f) {
  u32 b = __float_as_uint(f);
  return b ^ ((b >> 31) ? 0xFFFFFFFFu : 0x80000000u);
}

// ---------------- DPP helpers (VALU, no LDS pipe) ----------------
// 0x138 wave_shr1: dest lane n <- lane n-1.  0x130 wave_shl1: dest lane n <- lane n+1.
// bound_ctrl=true -> invalid src = 0.

template <int CTRL>
__device__ __forceinline__ u32 dpp32(u32 v) {
  return (u32)__builtin_amdgcn_update_dpp(0, (int)v, CTRL, 0xF, 0xF, true);
}

template <int CTRL>
__device__ __forceinline__ void dppmax64(u32& hi, u32& lo) {
  u32 h2 = dpp32<CTRL>(hi);
  u32 l2 = dpp32<CTRL>(lo);
  bool g = (h2 > hi) || (h2 == hi && l2 > lo);
  hi = g ? h2 : hi;
  lo = g ? l2 : lo;
}

// wave64 reduce; result valid in lane 63 (zero-fill: key 0 never wins)
__device__ __forceinline__ u64 wave_max_u64(u64 key) {
  u32 lo = (u32)key, hi = (u32)(key >> 32);
  dppmax64<0x111>(hi, lo); dppmax64<0x112>(hi, lo);
  dppmax64<0x114>(hi, lo); dppmax64<0x118>(hi, lo);
  dppmax64<0x142>(hi, lo); dppmax64<0x143>(hi, lo);
  return ((u64)hi << 32) | lo;
}

// 16-lane butterfly -> ALL lanes hold the result
__device__ __forceinline__ u64 bfly16_max_u64(u64 key) {
  u32 lo = (u32)key, hi = (u32)(key >> 32);
  dppmax64<0xB1>(hi, lo); dppmax64<0x4E>(hi, lo);
  dppmax64<0x141>(hi, lo); dppmax64<0x140>(hi, lo);
  return ((u64)hi << 32) | lo;
}

// ---------------- prep kernels (massively parallel) ----------------

#define TT 32
__global__ void transpose_k(const float* __restrict__ in, float* __restrict__ out) {
  __shared__ float tile[TT][TT + 1];
  int x = blockIdx.x * TT + threadIdx.x;
  int y = blockIdx.y * TT + threadIdx.y;
  for (int j = 0; j < TT; j += 8) tile[threadIdx.y + j][threadIdx.x] = in[(u64)(y + j) * NW + x];
  __syncthreads();
  x = blockIdx.y * TT + threadIdx.x;
  y = blockIdx.x * TT + threadIdx.y;
  for (int j = 0; j < TT; j += 8) out[(u64)(y + j) * NW + x] = tile[threadIdx.x][threadIdx.y + j];
}

// Natural layout: gumb[t*NW + i] = gumbel for element i at step t.
__global__ void gumbel_k(float* __restrict__ gumb) {
  long long idx = (long long)blockIdx.x * blockDim.x + threadIdx.x;
  if (idx >= (long long)NSTEPS * NW) return;
  int t = (int)(idx >> 12);
  int i = (int)(idx & (NW - 1));
  u32 kt0, kt1, kc0, kc1, ba, bb;
  tf2x32(0u, 42u, 0u, (u32)t, &kt0, &kt1);
  tf2x32(kt0, kt1, 0u, 1u, &kc0, &kc1);
  tf2x32(kc0, kc1, 0u, (u32)i, &ba, &bb);
  float u = unif01(ba ^ bb);
  if (u == 0.0f) u = 1.17549435e-38f;
  float t1 = (float)log((double)u);
  float t2 = (float)log((double)(-t1));
  gumb[idx] = -t2;
}

__global__ void posu_k(int* __restrict__ posArr, float* __restrict__ uArr) {
  int t = blockIdx.x * blockDim.x + threadIdx.x;
  if (t >= NSTEPS) return;
  u32 kt0, kt1, kp0, kp1, ku0, ku1, k2a, k2b, ra, rb, ua, ub;
  tf2x32(0u, 42u, 0u, (u32)t, &kt0, &kt1);
  tf2x32(kt0, kt1, 0u, 0u, &kp0, &kp1);
  tf2x32(kt0, kt1, 0u, 2u, &ku0, &ku1);
  tf2x32(kp0, kp1, 0u, 1u, &k2a, &k2b);
  tf2x32(k2a, k2b, 0u, 0u, &ra, &rb);
  posArr[t] = (int)((ra ^ rb) & (u32)(NW - 1));
  tf2x32(ku0, ku1, 0u, 0u, &ua, &ub);
  uArr[t] = unif01(ua ^ ub);
}

// ---------------- main chain kernel ----------------

// proposed sample element at index idx (reads pre-commit s_perm; uses np/pos/tm)
#define SAMPLE_AT(idx)                                                        \
  ((idx) < np ? (int)s_perm[(idx) + ((idx) >= pos)]                           \
              : ((idx) == np ? tm                                             \
                             : (int)s_perm[((idx)-1) + (((idx)-1) >= pos)]))

__global__ __launch_bounds__(NTHREADS)
void mcmc_fast13(const float* __restrict__ bigram,
                 const float* __restrict__ bigT,
                 const float* __restrict__ gumb,
                 const int* __restrict__ posArr,
                 const float* __restrict__ uArr,
                 const float* __restrict__ startv,
                 const float* __restrict__ endv,
                 int* __restrict__ out) {
  __shared__ u16    s_perm[NW];       // 8 KB   (random-access readers)
  __shared__ float2 s_rows[NW];       // 32 KB  (T[w], B[w]) for current tm
  __shared__ float  s_pairw[NW];      // 16 KB  (random-access: splitv)
  __shared__ u64    s_redu[NWAVES];
  __shared__ float  s_stm, s_etm, s_lpos, s_brgS, s_vn1, s_vn2;
  __shared__ int    s_accs, s_tmA;

  const int tid = threadIdx.x;
  const int lane = tid & 63;
  const int wid = tid >> 6;
  const int j0 = tid * 4;             // first owned element

  // ---- init: identity perm; pairw; stage step-0 rows (interleaved) ----
  for (int i = tid; i < NW; i += NTHREADS) s_perm[i] = (u16)i;
  ushort4 pq = make_ushort4((u16)j0, (u16)(j0 + 1), (u16)(j0 + 2), (u16)(j0 + 3));
  float4 pwq;
  pwq.x = bigram[(u64)j0 * NW + (j0 + 1)];
  pwq.y = bigram[(u64)(j0 + 1) * NW + (j0 + 2)];
  pwq.z = bigram[(u64)(j0 + 2) * NW + (j0 + 3)];
  pwq.w = (j0 + 3 < NW - 1) ? bigram[(u64)(j0 + 3) * NW + (j0 + 4)] : 0.0f;
  ((float4*)s_pairw)[tid] = pwq;

  int pos = posArr[0];
  int pn1 = posArr[1];
  float u_cur = uArr[0];
  float un1 = uArr[1];
  int tm = pos;                        // identity perm: perm[pos] == pos
  {
    float4 rb4 = ((const float4*)(bigram + (u64)tm * NW))[tid];
    float4 rt4 = ((const float4*)(bigT + (u64)tm * NW))[tid];
    ((float4*)(&s_rows[j0]))[0] = make_float4(rt4.x, rb4.x, rt4.y, rb4.y);
    ((float4*)(&s_rows[j0]))[1] = make_float4(rt4.z, rb4.z, rt4.w, rb4.w);
  }
  if (tid == 0) { s_stm = startv[tm]; s_etm = endv[tm]; }

  // wave0-carried uniform chain state (garbage in other waves, never read there)
  float start_cur = startv[0];
  float end_cur = endv[NW - 1];

  float4 g4 = ((const float4*)gumb)[tid];
  __syncthreads();

  for (int t = 0; t < NSTEPS; ++t) {
    // ---- Phase A ----
    const float gg[4] = {g4.x, g4.y, g4.z, g4.w};
    // speculative reject-branch staging (pn1 already in a register)
    const int tmR = (int)s_perm[pn1];
    const float4 rbR = ((const float4*)(bigram + (u64)tmR * NW))[tid];
    const float4 rtR = ((const float4*)(bigT + (u64)tmR * NW))[tid];
    float stmR = 0.0f, etmR = 0.0f;
    if (tid == 0) { stmR = startv[tmR]; etmR = endv[tmR]; }
    // next-next step stream prefetch
    int pn2; float un2;
    {
      int tn = (t + 1 < NSTEPS) ? (t + 1) : (NSTEPS - 1);
      int tn2 = (t + 2 < NSTEPS) ? (t + 2) : (NSTEPS - 1);
      g4 = ((const float4*)(gumb + ((u64)tn << 12)))[tid];   // for step t+1
      pn2 = posArr[tn2];
      un2 = uArr[tn2];
    }
    // wave0 uniform prefetch of all pos-only accept inputs (issued early, consumed in B)
    float stm_r = 0.0f, etm_r = 0.0f, remL = 0.0f, remR = 0.0f, brgv = 0.0f;
    float sv0m = 0.0f, ev1m = 0.0f;
    if (wid == 0) {
      stm_r = s_stm; etm_r = s_etm;
      int pl = (pos > 0) ? (int)s_perm[pos - 1] : 0;
      int pr = (pos < NW - 1) ? (int)s_perm[pos + 1] : 0;
      if (pos > 0)      remL = s_rows[pl].x;                 // B[P[pos-1], tm]
      if (pos < NW - 1) remR = s_rows[pr].y;                 // B[tm, P[pos+1]]
      if (pos > 0 && pos < NW - 1) brgv = bigram[(u64)pl * NW + pr];  // fresh bridge
      sv0m = startv[(int)s_perm[(0 >= pos) ? 1 : 0]];
      ev1m = endv[(int)s_perm[(NW - 2) + ((NW - 2) >= pos)]];
      if (lane == 0) s_brgS = brgv;
    }

    // perm block (registers) + cross-wave edges
    const int p0i = pq.x, p1i = pq.y, p2i = pq.z, p3i = pq.w;
    int pm1, pp4;
    {
      u32 lo = (u32)pq.x | ((u32)pq.y << 16);
      u32 hi = (u32)pq.z | ((u32)pq.w << 16);
      pm1 = (int)(dpp32<0x138>(hi) >> 16);                   // lane-1's p3 = perm[j0-1]
      pp4 = (int)(dpp32<0x130>(lo) & 0xFFFFu);               // lane+1's p0 = perm[j0+4]
      if (lane == 0)  pm1 = (tid > 0) ? (int)s_perm[j0 - 1] : 0;
      if (lane == 63) pp4 = (tid < NTHREADS - 1) ? (int)s_perm[j0 + 4] : 0;
    }
    // pairw cross-wave edge reads (values consumed lazily in Phase C on accept)
    float pwm1_e = 0.0f, pwp4_e = 0.0f;
    if (lane == 0 && tid > 0) pwm1_e = s_pairw[j0 - 1];
    if (lane == 63 && tid < NTHREADS - 1) pwp4_e = s_pairw[j0 + 4];

    // perm2 values for owned j (register selects)
    const int w0 = (j0     >= pos) ? p1i : p0i;
    const int w1 = (j0 + 1 >= pos) ? p2i : p1i;
    const int w2 = (j0 + 2 >= pos) ? p3i : p2i;
    const int w3 = (j0 + 3 >= pos) ? pp4 : p3i;
    const int wprev = ((j0 - 1) >= pos) ? p0i : pm1;         // perm2[j0-1]
    // interleaved gathers: f_k = (T[w_k], B[w_k])
    const float2 f0 = s_rows[w0];
    const float2 f1 = s_rows[w1];
    const float2 f2 = s_rows[w2];
    const float2 f3 = s_rows[w3];
    float tprev = __uint_as_float(dpp32<0x138>(__float_as_uint(f3.x)));
    if (lane == 0 && tid > 0) tprev = s_rows[wprev].x;
    // logits (bit-identical adds: T + B)
    float li0 = tprev + f0.y;
    float li1 = f0.x + f1.y;
    float li2 = f1.x + f2.y;
    float li3 = f2.x + f3.y;
    if (tid == 0)            li0 = s_stm + f0.y;
    if (tid == NTHREADS - 1) li3 = s_etm + f2.x;
    if ((pos >> 2) == tid) {
      int k = pos & 3;
      s_lpos = (k == 0) ? li0 : ((k == 1) ? li1 : ((k == 2) ? li2 : li3));
    }
    u64 best;
    {
      u64 b0 = ((u64)fkey(gg[0] + li0) << 32) | (u32)(NW - 1 - j0);
      u64 b1 = ((u64)fkey(gg[1] + li1) << 32) | (u32)(NW - 2 - j0);
      u64 b2 = ((u64)fkey(gg[2] + li2) << 32) | (u32)(NW - 3 - j0);
      u64 b3 = ((u64)fkey(gg[3] + li3) << 32) | (u32)(NW - 4 - j0);
      best = b0 > b1 ? b0 : b1;
      u64 b23 = b2 > b3 ? b2 : b3;
      if (b23 > best) best = b23;
    }
    best = wave_max_u64(best);
    if (lane == 63) s_redu[wid] = best;
    __syncthreads();                                                  // B1

    // ---- Phase B: wave0 ONLY (waves 1-15 go straight to B_mid) ----
    if (wid == 0) {
      u64 bb = bfly16_max_u64(s_redu[lane & 15]);
      const int np = NW - 1 - (int)(bb & 0xFFFFFFFFu);
      int ls_i = (np >= 1) ? ((np - 1) + ((np - 1) >= pos)) : 0;
      int rs_i = (np <= NW - 2) ? (np + (np >= pos)) : 0;
      const int l_s = (int)s_perm[ls_i];
      const int r_s = (int)s_perm[rs_i];
      const int tmA = SAMPLE_AT(pn1);
      float splitv = 0.0f;
      if (np > 0 && np < NW - 1) {
        int k_s = (np - 1) + ((np - 1) >= pos);
        splitv = (np == pos) ? brgv : s_pairw[k_s];          // O(1) LDS lookup
      }
      float vnpm1 = (np >= 1)      ? s_rows[l_s].x : 0.0f;
      float vnp   = (np <= NW - 2) ? s_rows[r_s].y : 0.0f;
      float sv0 = (np > 0) ? sv0m : stm_r;
      float ev1 = (np < NW - 1) ? ev1m : etm_r;
      float lposv = s_lpos;
      double delta = 0.0;
      if (pos > 0)                 delta -= (double)remL;
      if (pos < NW - 1)            delta -= (double)remR;
      if (pos > 0 && pos < NW - 1) delta += (double)brgv;
      if (np > 0)                  delta += (double)vnpm1;
      if (np < NW - 1)             delta += (double)vnp;
      if (np > 0 && np < NW - 1)   delta -= (double)splitv;
      delta += ((double)sv0 - (double)start_cur) + ((double)ev1 - (double)end_cur);
      float lnp = (np == 0) ? (stm_r + vnp)
                : ((np == NW - 1) ? (etm_r + vnpm1) : (vnpm1 + vnp));
      double ed = delta + ((double)lnp - (double)lposv);
      float a = fminf(1.0f, expf((float)ed));
      int acc = (a > u_cur) ? 1 : 0;
      if (lane == 0) { s_accs = acc; s_vn1 = vnpm1; s_vn2 = vnp; s_tmA = tmA; }
      if (acc) { start_cur = sv0; end_cur = ev1; }
    }
    __syncthreads();                                                  // B_mid

    // ---- Phase C: lazy accept work; reject path is ~free ----
    const int acc = s_accs;
    int tm_next = tmR;
    float4 rb = rbR, rt = rtR;
    ushort4 st = pq;
    if (acc) {
      tm_next = s_tmA;
      rb = ((const float4*)(bigram + (u64)tm_next * NW))[tid];
      rt = ((const float4*)(bigT + (u64)tm_next * NW))[tid];
      u64 bb = bfly16_max_u64(s_redu[lane & 15]);            // s_redu stable until B_end
      const int np = NW - 1 - (int)(bb & 0xFFFFFFFFu);
      // stash from registers
      st.x = (j0     < np) ? (u16)w0 : ((j0     == np) ? (u16)tm : (u16)wprev);
      st.y = (j0 + 1 < np) ? (u16)w1 : ((j0 + 1 == np) ? (u16)tm : (u16)w0);
      st.z = (j0 + 2 < np) ? (u16)w2 : ((j0 + 2 == np) ? (u16)tm : (u16)w1);
      st.w = (j0 + 3 < np) ? (u16)w3 : ((j0 + 3 == np) ? (u16)tm : (u16)w2);
      ((ushort4*)s_perm)[tid] = st;                          // 1 ds_write_b64
      // pairw maintenance (R14-verified formulas; pwm1/pwp4 via DPP on registers)
      float pwm1 = __uint_as_float(dpp32<0x138>(__float_as_uint(pwq.w)));
      float pwp4 = __uint_as_float(dpp32<0x130>(__float_as_uint(pwq.x)));
      if (lane == 0)  pwm1 = pwm1_e;
      if (lane == 63) pwp4 = pwp4_e;
      const float brgAll = s_brgS;
      float nv0, nv1, nv2, nv3;
      {
        float vA0 = (j0     < pos - 1) ? pwq.x : pwq.y;
        float vB0 = (j0 - 1 < pos - 1) ? pwm1  : pwq.x;
        nv0 = (j0 < np) ? vA0 : vB0;
        int kk0 = (j0 < np) ? j0 : j0 - 1;
        if (kk0 == pos - 1) nv0 = brgAll;

        float vA1 = (j0 + 1 < pos - 1) ? pwq.y : pwq.z;
        float vB1 = (j0     < pos - 1) ? pwq.x : pwq.y;
        nv1 = (j0 + 1 < np) ? vA1 : vB1;
        int kk1 = (j0 + 1 < np) ? j0 + 1 : j0;
        if (kk1 == pos - 1) nv1 = brgAll;

        float vA2 = (j0 + 2 < pos - 1) ? pwq.z : pwq.w;
        float vB2 = (j0 + 1 < pos - 1) ? pwq.y : pwq.z;
        nv2 = (j0 + 2 < np) ? vA2 : vB2;
        int kk2 = (j0 + 2 < np) ? j0 + 2 : j0 + 1;
        if (kk2 == pos - 1) nv2 = brgAll;

        float vA3 = (j0 + 3 < pos - 1) ? pwq.w : pwp4;
        float vB3 = (j0 + 2 < pos - 1) ? pwq.z : pwq.w;
        nv3 = (j0 + 3 < np) ? vA3 : vB3;
        int kk3 = (j0 + 3 < np) ? j0 + 3 : j0 + 2;
        if (kk3 == pos - 1) nv3 = brgAll;
      }
      const float vn1 = s_vn1, vn2 = s_vn2;
      float o0 = (j0     == np - 1) ? vn1 : ((j0     == np) ? vn2 : nv0);
      float o1 = (j0 + 1 == np - 1) ? vn1 : ((j0 + 1 == np) ? vn2 : nv1);
      float o2 = (j0 + 2 == np - 1) ? vn1 : ((j0 + 2 == np) ? vn2 : nv2);
      float o3 = (j0 + 3 == np - 1) ? vn1 : ((j0 + 3 == np) ? vn2 : nv3);
      if (j0 + 3 >= NW - 1) o3 = 0.0f;                       // pairw[NW-1] stays 0
      pwq = make_float4(o0, o1, o2, o3);
      ((float4*)s_pairw)[tid] = pwq;                         // 1 ds_write_b128
      if (tid == 0) { s_stm = startv[tm_next]; s_etm = endv[tm_next]; }
    } else {
      if (tid == 0) { s_stm = stmR; s_etm = etmR; }
    }
    ((float4*)(&s_rows[j0]))[0] = make_float4(rt.x, rb.x, rt.y, rb.y);
    ((float4*)(&s_rows[j0]))[1] = make_float4(rt.z, rb.z, rt.w, rb.w);
    pq = st;                            // post-commit perm block, carried in registers
    tm = tm_next;
    pos = pn1; u_cur = un1;
    pn1 = pn2; un1 = un2;

    // ---- emit thinned sample (pure register -> global; no LDS dependency) ----
    if ((t % 10) == 8) {
      int row = (t - 8) / 10;
      int4 o4;
      o4.x = (int)pq.x; o4.y = (int)pq.y; o4.z = (int)pq.z; o4.w = (int)pq.w;
      ((int4*)(out + (u64)row * NW))[tid] = o4;
    }
    __syncthreads();                                                  // B_end
  }
}

// ---------------- fallback (R2 kernel, verified) ----------------

__global__ __launch_bounds__(NTHREADS)
void mcmc_kernel(const float* __restrict__ bigram,
                 const float* __restrict__ startv,
                 const float* __restrict__ endv,
                 int* __restrict__ out) {
  __shared__ int    s_perm[NW];
  __shared__ float  s_logit[NW];
  __shared__ float  s_gath[NW];
  __shared__ float  s_redf[NWAVES];
  __shared__ u64    s_redu[NWAVES];
  __shared__ double s_redd[NWAVES];
  __shared__ float  s_m, s_Z, s_w;
  __shared__ int    s_pos, s_tm, s_np, s_acc;
  __shared__ u32    s_kcat0, s_kcat1, s_ku0, s_ku1;

  const int tid = threadIdx.x;
  const int lane = tid & 63;
  const int wid = tid >> 6;

  for (int i = tid; i < NW; i += NTHREADS) s_perm[i] = i;
  for (int j = tid; j < NW - 1; j += NTHREADS) s_gath[j] = bigram[(u64)j * NW + (j + 1)];
  __syncthreads();
  if (tid == 0) {
    float S = 0.0f;
    for (int j = 0; j < NW - 1; ++j) S += s_gath[j];
    S = S + startv[0];
    S = S + endv[NW - 1];
    s_w = S;
  }
  __syncthreads();

  for (int t = 0; t < NSTEPS; ++t) {
    if (tid == 0) {
      u32 kt0, kt1;
      tf2x32(0u, 42u, 0u, (u32)t, &kt0, &kt1);
      u32 kp0, kp1, kc0, kc1, ku0, ku1;
      tf2x32(kt0, kt1, 0u, 0u, &kp0, &kp1);
      tf2x32(kt0, kt1, 0u, 1u, &kc0, &kc1);
      tf2x32(kt0, kt1, 0u, 2u, &ku0, &ku1);
      u32 k2a, k2b, ra, rb;
      tf2x32(kp0, kp1, 0u, 1u, &k2a, &k2b);
      tf2x32(k2a, k2b, 0u, 0u, &ra, &rb);
      int pos = (int)((ra ^ rb) & (u32)(NW - 1));
      s_pos = pos;
      s_tm = s_perm[pos];
      s_kcat0 = kc0; s_kcat1 = kc1; s_ku0 = ku0; s_ku1 = ku1;
    }
    __syncthreads();
    const int pos = s_pos, tm = s_tm;

    float lmax = -3.402823466e+38f;
    for (int i = tid; i < NW; i += NTHREADS) {
      float li;
      if (i == 0) {
        int r = s_perm[(0 >= pos) ? 1 : 0];
        li = startv[tm] + bigram[(u64)tm * NW + r];
      } else if (i == NW - 1) {
        int l = s_perm[((NW - 2) >= pos) ? (NW - 1) : (NW - 2)];
        li = endv[tm] + bigram[(u64)l * NW + tm];
      } else {
        int l = s_perm[((i - 1) >= pos) ? i : (i - 1)];
        int r = s_perm[(i >= pos) ? (i + 1) : i];
        li = bigram[(u64)l * NW + tm] + bigram[(u64)tm * NW + r];
      }
      s_logit[i] = li;
      lmax = fmaxf(lmax, li);
    }
    for (int o = 32; o > 0; o >>= 1) lmax = fmaxf(lmax, __shfl_down(lmax, o, 64));
    if (lane == 0) s_redf[wid] = lmax;
    __syncthreads();
    if (tid == 0) {
      float m = s_redf[0];
      for (int w = 1; w < NWAVES; ++w) m = fmaxf(m, s_redf[w]);
      s_m = m;
    }
    __syncthreads();
    const float m = s_m;

    double zacc = 0.0;
    u64 best = 0;
    const u32 kc0 = s_kcat0, kc1 = s_kcat1;
    for (int i = tid; i < NW; i += NTHREADS) {
      float li = s_logit[i];
      float ex = (float)exp((double)(li - m));
      zacc += (double)ex;
      u32 ba, bb;
      tf2x32(kc0, kc1, 0u, (u32)i, &ba, &bb);
      float u = unif01(ba ^ bb);
      if (u == 0.0f) u = 1.17549435e-38f;
      float t1 = (float)log((double)u);
      float t2 = (float)log((double)(-t1));
      float g = -t2;
      float sv = g + li;
      u64 key = ((u64)fkey(sv) << 32) | (u32)(NW - 1 - i);
      if (key > best) best = key;
    }
    for (int o = 32; o > 0; o >>= 1) {
      u64 w = __shfl_down(best, o, 64);
      if (w > best) best = w;
      zacc += __shfl_down(zacc, o, 64);
    }
    if (lane == 0) { s_redu[wid] = best; s_redd[wid] = zacc; }
    __syncthreads();
    if (tid == 0) {
      u64 b = s_redu[0]; double z = s_redd[0];
      for (int w = 1; w < NWAVES; ++w) {
        if (s_redu[w] > b) b = s_redu[w];
        z += s_redd[w];
      }
      s_np = NW - 1 - (int)(b & 0xFFFFFFFFu);
      s_Z = (float)z;
    }
    __syncthreads();
    const int np = s_np;

    for (int j = tid; j < NW - 1; j += NTHREADS) {
      int a = (j < np) ? s_perm[j + (j >= pos)]
                       : ((j == np) ? tm : s_perm[(j - 1) + ((j - 1) >= pos)]);
      int j1 = j + 1;
      int b = (j1 < np) ? s_perm[j1 + (j1 >= pos)]
                        : ((j1 == np) ? tm : s_perm[(j1 - 1) + ((j1 - 1) >= pos)]);
      s_gath[j] = bigram[(u64)a * NW + b];
    }
    __syncthreads();

    if (tid == 0) {
      float S = 0.0f;
      for (int j = 0; j < NW - 1; ++j) S += s_gath[j];
      int s0 = (0 < np) ? s_perm[(0 >= pos) ? 1 : 0] : tm;
      int sl = ((NW - 1) == np) ? tm : s_perm[(NW - 2) + ((NW - 2) >= pos)];
      S = S + startv[s0];
      S = S + endv[sl];
      float dw = S - s_w;
      float e1 = (float)exp((double)dw);
      float en = (float)exp((double)(s_logit[np] - m));
      float eo = (float)exp((double)(s_logit[pos] - m));
      float pn = en / s_Z;
      float po = eo / s_Z;
      float acc = e1 * pn;
      acc = acc / po;
      acc = fminf(1.0f, acc);
      u32 ua, ub;
      tf2x32(s_ku0, s_ku1, 0u, 0u, &ua, &ub);
      float u = unif01(ua ^ ub);
      int accept = (acc > u) ? 1 : 0;
      s_acc = accept;
      if (accept) s_w = S;
    }
    __syncthreads();

    int stash[4];
    if (s_acc) {
      for (int k = 0; k < 4; ++k) {
        int i = tid + k * NTHREADS;
        stash[k] = (i < np) ? s_perm[i + (i >= pos)]
                            : ((i == np) ? tm : s_perm[(i - 1) + ((i - 1) >= pos)]);
      }
    }
    __syncthreads();
    if (s_acc) {
      for (int k = 0; k < 4; ++k) {
        int i = tid + k * NTHREADS;
        s_perm[i] = stash[k];
      }
    }
    __syncthreads();

    if (((t + 1) % 10) == 9) {
      int row = (t - 8) / 10;
      for (int i = tid; i < NW; i += NTHREADS) out[(u64)row * NW + i] = s_perm[i];
    }
    __syncthreads();
  }
}

extern "C" void kernel_launch(void* const* d_in, const int* in_sizes, int n_in,
                              void* d_out, int out_size, void* d_ws, size_t ws_size,
                              hipStream_t stream) {
  const float* bigram = (const float*)d_in[1];
  const float* startv = (const float*)d_in[2];
  const float* endv   = (const float*)d_in[3];
  int* out = (int*)d_out;

  const size_t needT = (size_t)NW * NW * sizeof(float);        // 64 MB
  const size_t needG = (size_t)NSTEPS * NW * sizeof(float);    // ~41.9 MB
  const size_t needP = (size_t)NSTEPS * (sizeof(int) + sizeof(float));

  if (ws_size >= needT + needG + needP) {
    float* bigT = (float*)d_ws;
    float* gumb = (float*)((char*)d_ws + needT);
    int* posArr = (int*)((char*)d_ws + needT + needG);
    float* uArr = (float*)((char*)d_ws + needT + needG + (size_t)NSTEPS * sizeof(int));
    hipLaunchKernelGGL(transpose_k, dim3(NW / TT, NW / TT), dim3(TT, 8), 0, stream,
                       bigram, bigT);
    long long ng = (long long)NSTEPS * NW;
    hipLaunchKernelGGL(gumbel_k, dim3((unsigned)((ng + 255) / 256)), dim3(256), 0, stream,
                       gumb);
    hipLaunchKernelGGL(posu_k, dim3((NSTEPS + 255) / 256), dim3(256), 0, stream,
                       posArr, uArr);
    hipLaunchKernelGGL(mcmc_fast13, dim3(1), dim3(NTHREADS), 0, stream,
                       bigram, bigT, gumb, posArr, uArr, startv, endv, out);
  } else {
    hipLaunchKernelGGL(mcmc_kernel, dim3(1), dim3(NTHREADS), 0, stream,
                       bigram, startv, endv, out);
  }
}